// Round 1
// baseline (2000.904 us; speedup 1.0000x reference)
//
#include <hip/hip_runtime.h>
#include <hip/hip_bf16.h>
#include <stdint.h>

#define TT 1024
#define EE 1024
#define HH 16
#define DD 64
#define BHN 32
#define HB 153
#define RECW 102
#define NEGF (-3.4028234663852886e38f)

// workspace layout (float element offsets)
#define OFF_Q  ((size_t)0)
#define OFF_K  (OFF_Q + (size_t)BHN*TT*DD)
#define OFF_V  (OFF_K + (size_t)BHN*TT*DD)
#define OFF_AW (OFF_V + (size_t)BHN*TT*DD)
#define OFF_M  (OFF_AW + (size_t)BHN*TT*TT)
#define OFF_S  (OFF_M + (size_t)BHN*TT)
#define OFF_AO (OFF_S + (size_t)BHN*TT)
#define OFF_END (OFF_AO + (size_t)BHN*TT*DD)

// ---------------- GEMM: Y = X @ W + b (optionally scaled, optionally head-split store)
__global__ __launch_bounds__(256) void k_proj(const float* __restrict__ X,
    const float* __restrict__ W, const float* __restrict__ bias,
    float* __restrict__ Y, float scale, int headsplit) {
  __shared__ float As[64][17];
  __shared__ float Bs[16][65];
  int tid = threadIdx.x;
  int tx = tid & 15, ty = tid >> 4;
  int r0 = blockIdx.y * 64, c0 = blockIdx.x * 64;
  float acc[4][4] = {};
  for (int k0 = 0; k0 < EE; k0 += 16) {
    {
      int i = tid >> 2;
      int kk = (tid & 3) * 4;
      const float4 a = *(const float4*)&X[(size_t)(r0 + i) * EE + k0 + kk];
      As[i][kk] = a.x; As[i][kk+1] = a.y; As[i][kk+2] = a.z; As[i][kk+3] = a.w;
    }
    {
      int kk = tid >> 4;
      int j = (tid & 15) * 4;
      const float4 b = *(const float4*)&W[(size_t)(k0 + kk) * EE + c0 + j];
      Bs[kk][j] = b.x; Bs[kk][j+1] = b.y; Bs[kk][j+2] = b.z; Bs[kk][j+3] = b.w;
    }
    __syncthreads();
    #pragma unroll
    for (int kk = 0; kk < 16; ++kk) {
      float a[4], b[4];
      #pragma unroll
      for (int u = 0; u < 4; ++u) a[u] = As[ty*4+u][kk];
      #pragma unroll
      for (int v = 0; v < 4; ++v) b[v] = Bs[kk][tx*4+v];
      #pragma unroll
      for (int u = 0; u < 4; ++u)
        #pragma unroll
        for (int v = 0; v < 4; ++v) acc[u][v] += a[u]*b[v];
    }
    __syncthreads();
  }
  #pragma unroll
  for (int u = 0; u < 4; ++u) {
    int r = r0 + ty*4 + u;
    #pragma unroll
    for (int v = 0; v < 4; ++v) {
      int c = c0 + tx*4 + v;
      float val = (acc[u][v] + bias[c]) * scale;
      if (headsplit) {
        int b_ = r >> 10, t_ = r & 1023, h_ = c >> 6, d_ = c & 63;
        Y[(((size_t)(b_*HH + h_) * TT) + t_) * DD + d_] = val;
      } else {
        Y[(size_t)r * EE + c] = val;
      }
    }
  }
}

// ---------------- batched QK^T: aw[bh][t][s] = sum_d q[bh][t][d]*k[bh][s][d]
__global__ __launch_bounds__(256) void k_qk(const float* __restrict__ q,
    const float* __restrict__ k, float* __restrict__ aw) {
  int bh = blockIdx.z;
  int t0 = blockIdx.y * 64, s0 = blockIdx.x * 64;
  if (s0 > t0 + 63) return;  // strictly above diagonal: never read
  __shared__ float Qs[64][65];
  __shared__ float Ks[64][65];
  int tid = threadIdx.x;
  const float* qb = q + (size_t)bh * TT * DD;
  const float* kb = k + (size_t)bh * TT * DD;
  #pragma unroll
  for (int u = 0; u < 4; ++u) {
    int fi = tid + u * 256;
    int row = fi >> 4, c4 = (fi & 15) * 4;
    float4 a = *(const float4*)&qb[(size_t)(t0 + row) * DD + c4];
    Qs[row][c4] = a.x; Qs[row][c4+1] = a.y; Qs[row][c4+2] = a.z; Qs[row][c4+3] = a.w;
    float4 b = *(const float4*)&kb[(size_t)(s0 + row) * DD + c4];
    Ks[row][c4] = b.x; Ks[row][c4+1] = b.y; Ks[row][c4+2] = b.z; Ks[row][c4+3] = b.w;
  }
  __syncthreads();
  int tx = tid & 15, ty = tid >> 4;
  float acc[4][4] = {};
  #pragma unroll 8
  for (int kk = 0; kk < 64; ++kk) {
    float a[4], b[4];
    #pragma unroll
    for (int u = 0; u < 4; ++u) a[u] = Qs[ty*4+u][kk];
    #pragma unroll
    for (int v = 0; v < 4; ++v) b[v] = Ks[tx*4+v][kk];
    #pragma unroll
    for (int u = 0; u < 4; ++u)
      #pragma unroll
      for (int v = 0; v < 4; ++v) acc[u][v] += a[u]*b[v];
  }
  float* awb = aw + (size_t)bh * TT * TT;
  #pragma unroll
  for (int u = 0; u < 4; ++u) {
    int t_ = t0 + ty*4 + u;
    #pragma unroll
    for (int v = 0; v < 4; ++v)
      awb[(size_t)t_ * TT + s0 + tx*4 + v] = acc[u][v];
  }
}

// ---------------- per-row softmax stats over causal prefix
__global__ __launch_bounds__(256) void k_rowstats(const float* __restrict__ aw,
    float* __restrict__ Mv, float* __restrict__ Sv) {
  int bh = blockIdx.y;
  int wid = threadIdx.x >> 6, lane = threadIdx.x & 63;
  int t = blockIdx.x * 4 + wid;
  const float* row = aw + ((size_t)bh * TT + t) * TT;
  float vals[16];
  float m = NEGF;
  #pragma unroll
  for (int i = 0; i < 16; ++i) {
    int j = lane + 64*i;
    vals[i] = (j <= t) ? row[j] : NEGF;
    m = fmaxf(m, vals[i]);
  }
  for (int o = 32; o; o >>= 1) m = fmaxf(m, __shfl_xor(m, o));
  float s = 0.f;
  #pragma unroll
  for (int i = 0; i < 16; ++i) {
    int j = lane + 64*i;
    if (j <= t) s += expf(vals[i] - m);
  }
  for (int o = 32; o; o >>= 1) s += __shfl_xor(s, o);
  if (lane == 0) { Mv[(size_t)bh*TT + t] = m; Sv[(size_t)bh*TT + t] = s; }
}

// ---------------- serial heavy-hitter scan: one wave per bh
__global__ __launch_bounds__(64) void k_scan(const float* __restrict__ aw,
    const float* __restrict__ Mv, const float* __restrict__ Sv,
    unsigned long long* __restrict__ maskbits) {
  int bh = blockIdx.x;
  int lane = threadIdx.x;
  const float* awb = aw + (size_t)bh * TT * TT;
  const float* Mb = Mv + (size_t)bh * TT;
  const float* Sb = Sv + (size_t)bh * TT;
  unsigned long long* mb = maskbits + (size_t)bh * TT * 16;

  __shared__ float rowbuf[TT];
  __shared__ unsigned long long bits[16];

  // rows 0..hb-1: init block (cols < hb)
  for (int r = lane; r < HB; r += 64) {
    unsigned long long* w = mb + (size_t)r * 16;
    w[0] = ~0ull; w[1] = ~0ull; w[2] = (1ull << 25) - 1;
    #pragma unroll
    for (int i = 3; i < 16; ++i) w[i] = 0ull;
  }

  // slots: 3 per lane
  int col[3]; float sc[3];
  #pragma unroll
  for (int s = 0; s < 3; ++s) {
    int c = lane + 64*s;
    col[s] = (c < HB) ? c : -1;
    sc[s] = 0.f;
  }
  // init scores: acc[c] = sum_{i=c..hb-1} exp(aw[i][c]-M[i]) / S[i]
  for (int i = 0; i < HB; ++i) {
    float Mi = Mb[i], Si = Sb[i];
    #pragma unroll
    for (int s = 0; s < 3; ++s) {
      if (col[s] >= 0 && col[s] <= i)
        sc[s] += expf(awb[(size_t)i * TT + col[s]] - Mi) / Si;
    }
  }

  // prefetch row HB
  float4 nxt[4];
  {
    const float4* src = (const float4*)(awb + (size_t)HB * TT);
    #pragma unroll
    for (int i = 0; i < 4; ++i) nxt[i] = src[lane + 64*i];
  }

  for (int t = HB; t < TT; ++t) {
    __syncthreads();
    float4* rb = (float4*)rowbuf;
    #pragma unroll
    for (int i = 0; i < 4; ++i) rb[lane + 64*i] = nxt[i];
    __syncthreads();
    if (t + 1 < TT) {
      const float4* src = (const float4*)(awb + (size_t)(t+1) * TT);
      #pragma unroll
      for (int i = 0; i < 4; ++i) nxt[i] = src[lane + 64*i];
    }
    float Mt = Mb[t], St = Sb[t];

    // eviction: min score, tie -> larger col evicted
    unsigned long long best = ~0ull;
    unsigned long long key[3];
    #pragma unroll
    for (int s = 0; s < 3; ++s) {
      if (col[s] >= 0) {
        key[s] = ((unsigned long long)__float_as_uint(sc[s]) << 32)
               | (unsigned)(~(unsigned)col[s]);
        best = best < key[s] ? best : key[s];
      } else key[s] = ~0ull;
    }
    for (int o = 32; o; o >>= 1) {
      unsigned long long other = __shfl_xor(best, o);
      best = best < other ? best : other;
    }

    // update slots
    #pragma unroll
    for (int s = 0; s < 3; ++s) {
      if (col[s] >= 0) {
        int c;
        if (key[s] == best) { c = t; sc[s] = 0.f; }  // evicted slot -> token t
        else c = col[s];
        col[s] = c;
        sc[s] += expf(rowbuf[c] - Mt) / St;
      }
    }

    // write mask bits for row t (= survivors + t)
    if (lane < 16) bits[lane] = 0ull;
    __syncthreads();
    #pragma unroll
    for (int s = 0; s < 3; ++s)
      if (col[s] >= 0)
        atomicOr(&bits[col[s] >> 6], 1ull << (col[s] & 63));
    __syncthreads();
    if (lane < 16) mb[(size_t)t * 16 + lane] = bits[lane];
  }
}

// ---------------- masked softmax + PV
__global__ __launch_bounds__(256) void k_attn(const float* __restrict__ aw,
    const unsigned long long* __restrict__ maskbits,
    const float* __restrict__ v, float* __restrict__ ao) {
  int bh = blockIdx.y, t = blockIdx.x;
  int tid = threadIdx.x;
  const float* row = aw + ((size_t)bh * TT + t) * TT;
  const unsigned long long* mbr = maskbits + ((size_t)bh * TT + t) * 16;
  __shared__ float p[TT];
  __shared__ float red[8];
  __shared__ float pv[4][64];
  __shared__ unsigned long long wbits[16];
  if (tid < 16) wbits[tid] = mbr[tid];
  __syncthreads();

  float vals[4]; bool ok[4];
  float m = NEGF;
  #pragma unroll
  for (int i = 0; i < 4; ++i) {
    int j = tid + 256*i;
    bool allow = (j <= t) && (((wbits[j>>6] >> (j&63)) & 1ull) || (j + RECW >= t));
    ok[i] = allow;
    vals[i] = allow ? row[j] : NEGF;
    m = fmaxf(m, vals[i]);
  }
  for (int o = 32; o; o >>= 1) m = fmaxf(m, __shfl_xor(m, o));
  int wid = tid >> 6;
  if ((tid & 63) == 0) red[wid] = m;
  __syncthreads();
  m = fmaxf(fmaxf(red[0], red[1]), fmaxf(red[2], red[3]));

  float s = 0.f;
  float e[4];
  #pragma unroll
  for (int i = 0; i < 4; ++i) { e[i] = ok[i] ? expf(vals[i] - m) : 0.f; s += e[i]; }
  for (int o = 32; o; o >>= 1) s += __shfl_xor(s, o);
  if ((tid & 63) == 0) red[4 + wid] = s;
  __syncthreads();
  s = red[4] + red[5] + red[6] + red[7];
  float inv = 1.f / s;
  #pragma unroll
  for (int i = 0; i < 4; ++i) p[tid + 256*i] = e[i] * inv;
  __syncthreads();

  int g = tid >> 6, d = tid & 63;
  const float* vb = v + (size_t)bh * TT * DD;
  float acc = 0.f;
  int lim = t + 1 - g*256; if (lim > 256) lim = 256;
  for (int i = 0; i < lim; ++i) {
    int j = g * 256 + i;
    acc += p[j] * vb[(size_t)j * DD + d];
  }
  pv[g][d] = acc;
  __syncthreads();
  if (tid < 64) {
    float r = pv[0][tid] + pv[1][tid] + pv[2][tid] + pv[3][tid];
    int b_ = bh >> 4, h_ = bh & 15;
    ao[((size_t)b_ * TT + t) * EE + h_ * DD + tid] = r;
  }
}

extern "C" void kernel_launch(void* const* d_in, const int* in_sizes, int n_in,
                              void* d_out, int out_size, void* d_ws, size_t ws_size,
                              hipStream_t stream) {
  const float* hs = (const float*)d_in[0];
  // d_in[1] = attention_mask (causal; semantics hardcoded)
  const float* Wq = (const float*)d_in[2];
  const float* bq = (const float*)d_in[3];
  const float* Wk = (const float*)d_in[4];
  const float* bk = (const float*)d_in[5];
  const float* Wv = (const float*)d_in[6];
  const float* bv = (const float*)d_in[7];
  const float* Wo = (const float*)d_in[8];
  const float* bo = (const float*)d_in[9];
  float* out = (float*)d_out;

  float* ws = (float*)d_ws;
  float* q  = ws + OFF_Q;
  float* k  = ws + OFF_K;
  float* v  = ws + OFF_V;
  float* aw = ws + OFF_AW;
  float* Mv = ws + OFF_M;
  float* Sv = ws + OFF_S;
  float* ao = ws + OFF_AO;
  unsigned long long* maskbits = (unsigned long long*)(ws + OFF_END);

  dim3 gproj(16, 32);
  k_proj<<<gproj, 256, 0, stream>>>(hs, Wq, bq, q, 0.125f, 1);
  k_proj<<<gproj, 256, 0, stream>>>(hs, Wk, bk, k, 1.0f, 1);
  k_proj<<<gproj, 256, 0, stream>>>(hs, Wv, bv, v, 1.0f, 1);

  dim3 gqk(16, 16, BHN);
  k_qk<<<gqk, 256, 0, stream>>>(q, k, aw);

  dim3 grs(TT/4, BHN);
  k_rowstats<<<grs, 256, 0, stream>>>(aw, Mv, Sv);

  k_scan<<<BHN, 64, 0, stream>>>(aw, Mv, Sv, maskbits);

  dim3 gat(TT, BHN);
  k_attn<<<gat, 256, 0, stream>>>(aw, maskbits, v, ao);

  k_proj<<<gproj, 256, 0, stream>>>(ao, Wo, bo, out, 1.0f, 0);
}

// Round 2
// 1647.526 us; speedup vs baseline: 1.2145x; 1.2145x over previous
//
#include <hip/hip_runtime.h>
#include <hip/hip_bf16.h>
#include <stdint.h>

#define TT 1024
#define EE 1024
#define HH 16
#define DD 64
#define BHN 32
#define HB 153
#define RECW 102
#define NEGF (-3.4028234663852886e38f)

typedef unsigned long long ull;

// workspace layout (float element offsets)
#define OFF_Q  ((size_t)0)
#define OFF_K  (OFF_Q + (size_t)BHN*TT*DD)
#define OFF_V  (OFF_K + (size_t)BHN*TT*DD)
#define OFF_AW (OFF_V + (size_t)BHN*TT*DD)
#define OFF_M  (OFF_AW + (size_t)BHN*TT*TT)
#define OFF_S  (OFF_M + (size_t)BHN*TT)
#define OFF_AO (OFF_S + (size_t)BHN*TT)
#define OFF_END (OFF_AO + (size_t)BHN*TT*DD)
// after OFF_END: initacc float[BHN*256], evict int[BHN*1024]

// ---------------- GEMM: Y = X @ W + b (optionally scaled, optionally head-split store)
__global__ __launch_bounds__(256) void k_proj(const float* __restrict__ X,
    const float* __restrict__ W, const float* __restrict__ bias,
    float* __restrict__ Y, float scale, int headsplit) {
  __shared__ float As[64][17];
  __shared__ float Bs[16][65];
  int tid = threadIdx.x;
  int tx = tid & 15, ty = tid >> 4;
  int r0 = blockIdx.y * 64, c0 = blockIdx.x * 64;
  float acc[4][4] = {};
  for (int k0 = 0; k0 < EE; k0 += 16) {
    {
      int i = tid >> 2;
      int kk = (tid & 3) * 4;
      const float4 a = *(const float4*)&X[(size_t)(r0 + i) * EE + k0 + kk];
      As[i][kk] = a.x; As[i][kk+1] = a.y; As[i][kk+2] = a.z; As[i][kk+3] = a.w;
    }
    {
      int kk = tid >> 4;
      int j = (tid & 15) * 4;
      const float4 b = *(const float4*)&W[(size_t)(k0 + kk) * EE + c0 + j];
      Bs[kk][j] = b.x; Bs[kk][j+1] = b.y; Bs[kk][j+2] = b.z; Bs[kk][j+3] = b.w;
    }
    __syncthreads();
    #pragma unroll
    for (int kk = 0; kk < 16; ++kk) {
      float a[4], b[4];
      #pragma unroll
      for (int u = 0; u < 4; ++u) a[u] = As[ty*4+u][kk];
      #pragma unroll
      for (int v = 0; v < 4; ++v) b[v] = Bs[kk][tx*4+v];
      #pragma unroll
      for (int u = 0; u < 4; ++u)
        #pragma unroll
        for (int v = 0; v < 4; ++v) acc[u][v] += a[u]*b[v];
    }
    __syncthreads();
  }
  #pragma unroll
  for (int u = 0; u < 4; ++u) {
    int r = r0 + ty*4 + u;
    #pragma unroll
    for (int v = 0; v < 4; ++v) {
      int c = c0 + tx*4 + v;
      float val = (acc[u][v] + bias[c]) * scale;
      if (headsplit) {
        int b_ = r >> 10, t_ = r & 1023, h_ = c >> 6, d_ = c & 63;
        Y[(((size_t)(b_*HH + h_) * TT) + t_) * DD + d_] = val;
      } else {
        Y[(size_t)r * EE + c] = val;
      }
    }
  }
}

// ---------------- batched QK^T
__global__ __launch_bounds__(256) void k_qk(const float* __restrict__ q,
    const float* __restrict__ k, float* __restrict__ aw) {
  int bh = blockIdx.z;
  int t0 = blockIdx.y * 64, s0 = blockIdx.x * 64;
  if (s0 > t0 + 63) return;
  __shared__ float Qs[64][65];
  __shared__ float Ks[64][65];
  int tid = threadIdx.x;
  const float* qb = q + (size_t)bh * TT * DD;
  const float* kb = k + (size_t)bh * TT * DD;
  #pragma unroll
  for (int u = 0; u < 4; ++u) {
    int fi = tid + u * 256;
    int row = fi >> 4, c4 = (fi & 15) * 4;
    float4 a = *(const float4*)&qb[(size_t)(t0 + row) * DD + c4];
    Qs[row][c4] = a.x; Qs[row][c4+1] = a.y; Qs[row][c4+2] = a.z; Qs[row][c4+3] = a.w;
    float4 b = *(const float4*)&kb[(size_t)(s0 + row) * DD + c4];
    Ks[row][c4] = b.x; Ks[row][c4+1] = b.y; Ks[row][c4+2] = b.z; Ks[row][c4+3] = b.w;
  }
  __syncthreads();
  int tx = tid & 15, ty = tid >> 4;
  float acc[4][4] = {};
  #pragma unroll 8
  for (int kk = 0; kk < 64; ++kk) {
    float a[4], b[4];
    #pragma unroll
    for (int u = 0; u < 4; ++u) a[u] = Qs[ty*4+u][kk];
    #pragma unroll
    for (int v = 0; v < 4; ++v) b[v] = Ks[tx*4+v][kk];
    #pragma unroll
    for (int u = 0; u < 4; ++u)
      #pragma unroll
      for (int v = 0; v < 4; ++v) acc[u][v] += a[u]*b[v];
  }
  float* awb = aw + (size_t)bh * TT * TT;
  #pragma unroll
  for (int u = 0; u < 4; ++u) {
    int t_ = t0 + ty*4 + u;
    #pragma unroll
    for (int v = 0; v < 4; ++v)
      awb[(size_t)t_ * TT + s0 + tx*4 + v] = acc[u][v];
  }
}

// ---------------- per-row softmax stats over causal prefix
__global__ __launch_bounds__(256) void k_rowstats(const float* __restrict__ aw,
    float* __restrict__ Mv, float* __restrict__ Sv) {
  int bh = blockIdx.y;
  int wid = threadIdx.x >> 6, lane = threadIdx.x & 63;
  int t = blockIdx.x * 4 + wid;
  const float* row = aw + ((size_t)bh * TT + t) * TT;
  float vals[16];
  float m = NEGF;
  #pragma unroll
  for (int i = 0; i < 16; ++i) {
    int j = lane + 64*i;
    vals[i] = (j <= t) ? row[j] : NEGF;
    m = fmaxf(m, vals[i]);
  }
  for (int o = 32; o; o >>= 1) m = fmaxf(m, __shfl_xor(m, o));
  float s = 0.f;
  #pragma unroll
  for (int i = 0; i < 16; ++i) {
    int j = lane + 64*i;
    if (j <= t) s += expf(vals[i] - m);
  }
  for (int o = 32; o; o >>= 1) s += __shfl_xor(s, o);
  if (lane == 0) { Mv[(size_t)bh*TT + t] = m; Sv[(size_t)bh*TT + t] = s; }
}

// ---------------- parallel init of heavy-hitter scores:
// acc[c] = sum_{i=c..HB-1} exp(aw[i][c]-M[i]) / S[i]
__global__ __launch_bounds__(256) void k_init_acc(const float* __restrict__ aw,
    const float* __restrict__ Mv, const float* __restrict__ Sv,
    float* __restrict__ initacc) {
  int bh = blockIdx.x;
  int c = threadIdx.x;
  float val = 0.f;
  if (c < HB) {
    const float* awb = aw + (size_t)bh * TT * TT;
    const float* Mb = Mv + (size_t)bh * TT;
    const float* Sb = Sv + (size_t)bh * TT;
    for (int i = c; i < HB; ++i)
      val += expf(awb[(size_t)i * TT + c] - Mb[i]) / Sb[i];
  }
  initacc[(size_t)bh * 256 + c] = val;
}

// ---------------- serial heavy-hitter scan: one wave per bh, no barriers in loop
__device__ __forceinline__ void scan_step(int t, float4 (&P)[4],
    float (&sc)[3], int (&col)[3],
    float* __restrict__ rowbuf, const float* __restrict__ Ml,
    const float* __restrict__ Sl, int* __restrict__ ev,
    const float* __restrict__ awb, int lane) {
  float* rb  = rowbuf + (t & 1) * TT;
  float* rbn = rowbuf + ((t + 1) & 1) * TT;
  // early LDS reads: addresses known before eviction decision
  float r0 = (col[0] >= 0) ? rb[col[0]] : 0.f;
  float r1 = (col[1] >= 0) ? rb[col[1]] : 0.f;
  float r2 = (col[2] >= 0) ? rb[col[2]] : 0.f;
  float rd = rb[t];                     // diagonal aw[t][t] (broadcast)
  float Mt = Ml[t], St = Sl[t];
  // stage row t+1 into the other LDS buffer; refill the register pipe (row t+3)
  if (t + 1 < TT) {
    float4* w = (float4*)rbn;
    #pragma unroll
    for (int i = 0; i < 4; ++i) w[lane + 64 * i] = P[i];
  }
  if (t + 3 < TT) {
    const float4* src = (const float4*)(awb + (size_t)(t + 3) * TT);
    #pragma unroll
    for (int i = 0; i < 4; ++i) P[i] = src[lane + 64 * i];
  }
  // updates (parallel to the reduce; off the serial chain)
  float u0 = expf(r0 - Mt) / St;
  float u1 = expf(r1 - Mt) / St;
  float u2 = expf(r2 - Mt) / St;
  float ud = expf(rd - Mt) / St;        // new token's score
  // keys: min score evicted; tie -> larger col evicted (ref top_k keeps lower idx)
  ull kk[3];
  kk[0] = (col[0] >= 0) ? ((((ull)__float_as_uint(sc[0])) << 32) | (unsigned)(1023 - col[0])) : ~0ull;
  kk[1] = (col[1] >= 0) ? ((((ull)__float_as_uint(sc[1])) << 32) | (unsigned)(1023 - col[1])) : ~0ull;
  kk[2] = (col[2] >= 0) ? ((((ull)__float_as_uint(sc[2])) << 32) | (unsigned)(1023 - col[2])) : ~0ull;
  ull b = kk[0] < kk[1] ? kk[0] : kk[1];
  b = b < kk[2] ? b : kk[2];
  #pragma unroll
  for (int o = 32; o; o >>= 1) {
    ull other = __shfl_xor(b, o);
    b = other < b ? other : b;
  }
  // select
  #pragma unroll
  for (int s = 0; s < 3; ++s) {
    if (col[s] >= 0) {
      if (kk[s] == b) { ev[col[s]] = t; col[s] = t; sc[s] = ud; }
      else sc[s] += (s == 0 ? u0 : (s == 1 ? u1 : u2));
    }
  }
}

__global__ __launch_bounds__(64) void k_scan(const float* __restrict__ aw,
    const float* __restrict__ Mv, const float* __restrict__ Sv,
    const float* __restrict__ initacc, int* __restrict__ evict_g) {
  int bh = blockIdx.x;
  int lane = threadIdx.x;
  const float* awb = aw + (size_t)bh * TT * TT;
  __shared__ float rowbuf[2 * TT];
  __shared__ float Ml[TT];
  __shared__ float Sl[TT];
  __shared__ int ev[TT];
  for (int i = lane; i < TT; i += 64) {
    Ml[i] = Mv[(size_t)bh * TT + i];
    Sl[i] = Sv[(size_t)bh * TT + i];
    ev[i] = 0x7fffffff;
  }
  // slots
  int col[3]; float sc[3];
  #pragma unroll
  for (int s = 0; s < 3; ++s) {
    int c = lane + 64 * s;
    col[s] = (c < HB) ? c : -1;
    sc[s] = (c < HB) ? initacc[(size_t)bh * 256 + c] : 0.f;
  }
  // row HB into rowbuf[HB&1]; pipeline regs: PA=row HB+1, PB=row HB+2
  {
    float4* w = (float4*)(rowbuf + (HB & 1) * TT);
    const float4* src = (const float4*)(awb + (size_t)HB * TT);
    #pragma unroll
    for (int i = 0; i < 4; ++i) w[lane + 64 * i] = src[lane + 64 * i];
  }
  float4 PA[4], PB[4];
  {
    const float4* sa = (const float4*)(awb + (size_t)(HB + 1) * TT);
    const float4* sb = (const float4*)(awb + (size_t)(HB + 2) * TT);
    #pragma unroll
    for (int i = 0; i < 4; ++i) { PA[i] = sa[lane + 64 * i]; PB[i] = sb[lane + 64 * i]; }
  }
  __syncthreads();

  scan_step(HB, PA, sc, col, rowbuf, Ml, Sl, ev, awb, lane);      // t=153
  #pragma unroll 1
  for (int t = HB + 1; t < TT - 2; t += 2) {
    scan_step(t,     PB, sc, col, rowbuf, Ml, Sl, ev, awb, lane);
    scan_step(t + 1, PA, sc, col, rowbuf, Ml, Sl, ev, awb, lane);
  }
  scan_step(TT - 2, PB, sc, col, rowbuf, Ml, Sl, ev, awb, lane);  // t=1022
  scan_step(TT - 1, PA, sc, col, rowbuf, Ml, Sl, ev, awb, lane);  // t=1023

  __syncthreads();
  int4* dst = (int4*)(evict_g + (size_t)bh * TT);
  const int4* srcv = (const int4*)ev;
  #pragma unroll
  for (int i = 0; i < 4; ++i) dst[lane + 64 * i] = srcv[lane + 64 * i];
}

// ---------------- masked softmax + PV using evict_time
__global__ __launch_bounds__(256) void k_attn(const float* __restrict__ aw,
    const int* __restrict__ evict_g,
    const float* __restrict__ v, float* __restrict__ ao) {
  int bh = blockIdx.y, t = blockIdx.x;
  int tid = threadIdx.x;
  const float* row = aw + ((size_t)bh * TT + t) * TT;
  __shared__ float p[TT];
  __shared__ float red[8];
  __shared__ float pv[4][64];
  __shared__ int et[TT];
  ((int4*)et)[tid] = ((const int4*)(evict_g + (size_t)bh * TT))[tid];
  __syncthreads();

  float vals[4]; bool ok[4];
  float m = NEGF;
  #pragma unroll
  for (int i = 0; i < 4; ++i) {
    int j = tid + 256*i;
    bool allow = (j <= t) && ((et[j] > t) || (j + RECW >= t));
    ok[i] = allow;
    vals[i] = allow ? row[j] : NEGF;
    m = fmaxf(m, vals[i]);
  }
  for (int o = 32; o; o >>= 1) m = fmaxf(m, __shfl_xor(m, o));
  int wid = tid >> 6;
  if ((tid & 63) == 0) red[wid] = m;
  __syncthreads();
  m = fmaxf(fmaxf(red[0], red[1]), fmaxf(red[2], red[3]));

  float s = 0.f;
  float e[4];
  #pragma unroll
  for (int i = 0; i < 4; ++i) { e[i] = ok[i] ? expf(vals[i] - m) : 0.f; s += e[i]; }
  for (int o = 32; o; o >>= 1) s += __shfl_xor(s, o);
  if ((tid & 63) == 0) red[4 + wid] = s;
  __syncthreads();
  s = red[4] + red[5] + red[6] + red[7];
  float inv = 1.f / s;
  #pragma unroll
  for (int i = 0; i < 4; ++i) p[tid + 256*i] = e[i] * inv;
  __syncthreads();

  int g = tid >> 6, d = tid & 63;
  const float* vb = v + (size_t)bh * TT * DD;
  float acc = 0.f;
  int lim = t + 1 - g*256; if (lim > 256) lim = 256;
  for (int i = 0; i < lim; ++i) {
    int j = g * 256 + i;
    acc += p[j] * vb[(size_t)j * DD + d];
  }
  pv[g][d] = acc;
  __syncthreads();
  if (tid < 64) {
    float r = pv[0][tid] + pv[1][tid] + pv[2][tid] + pv[3][tid];
    int b_ = bh >> 4, h_ = bh & 15;
    ao[((size_t)b_ * TT + t) * EE + h_ * DD + tid] = r;
  }
}

extern "C" void kernel_launch(void* const* d_in, const int* in_sizes, int n_in,
                              void* d_out, int out_size, void* d_ws, size_t ws_size,
                              hipStream_t stream) {
  const float* hs = (const float*)d_in[0];
  const float* Wq = (const float*)d_in[2];
  const float* bq = (const float*)d_in[3];
  const float* Wk = (const float*)d_in[4];
  const float* bk = (const float*)d_in[5];
  const float* Wv = (const float*)d_in[6];
  const float* bv = (const float*)d_in[7];
  const float* Wo = (const float*)d_in[8];
  const float* bo = (const float*)d_in[9];
  float* out = (float*)d_out;

  float* ws = (float*)d_ws;
  float* q  = ws + OFF_Q;
  float* k  = ws + OFF_K;
  float* v  = ws + OFF_V;
  float* aw = ws + OFF_AW;
  float* Mv = ws + OFF_M;
  float* Sv = ws + OFF_S;
  float* ao = ws + OFF_AO;
  float* initacc = ws + OFF_END;
  int* evict = (int*)(ws + OFF_END + (size_t)BHN * 256);

  dim3 gproj(16, 32);
  k_proj<<<gproj, 256, 0, stream>>>(hs, Wq, bq, q, 0.125f, 1);
  k_proj<<<gproj, 256, 0, stream>>>(hs, Wk, bk, k, 1.0f, 1);
  k_proj<<<gproj, 256, 0, stream>>>(hs, Wv, bv, v, 1.0f, 1);

  dim3 gqk(16, 16, BHN);
  k_qk<<<gqk, 256, 0, stream>>>(q, k, aw);

  dim3 grs(TT/4, BHN);
  k_rowstats<<<grs, 256, 0, stream>>>(aw, Mv, Sv);

  k_init_acc<<<BHN, 256, 0, stream>>>(aw, Mv, Sv, initacc);

  k_scan<<<BHN, 64, 0, stream>>>(aw, Mv, Sv, initacc, evict);

  dim3 gat(TT, BHN);
  k_attn<<<gat, 256, 0, stream>>>(aw, evict, v, ao);

  k_proj<<<gproj, 256, 0, stream>>>(ao, Wo, bo, out, 1.0f, 0);
}

// Round 3
// 1379.728 us; speedup vs baseline: 1.4502x; 1.1941x over previous
//
#include <hip/hip_runtime.h>
#include <hip/hip_bf16.h>
#include <stdint.h>

#define TT 1024
#define EE 1024
#define HH 16
#define DD 64
#define BHN 32
#define HB 153
#define RECW 102
#define NEGF (-3.4028234663852886e38f)

typedef unsigned long long ull;

// workspace layout (float element offsets)
#define OFF_Q  ((size_t)0)
#define OFF_K  (OFF_Q + (size_t)BHN*TT*DD)
#define OFF_V  (OFF_K + (size_t)BHN*TT*DD)
#define OFF_AW (OFF_V + (size_t)BHN*TT*DD)
#define OFF_M  (OFF_AW + (size_t)BHN*TT*TT)
#define OFF_S  (OFF_M + (size_t)BHN*TT)
#define OFF_AO (OFF_S + (size_t)BHN*TT)
#define OFF_END (OFF_AO + (size_t)BHN*TT*DD)
// after OFF_END: initacc float[BHN*256], evict int[BHN*1024]

// ---------------- GEMM: Y = X @ W + b (optionally scaled, optionally head-split store)
__global__ __launch_bounds__(256) void k_proj(const float* __restrict__ X,
    const float* __restrict__ W, const float* __restrict__ bias,
    float* __restrict__ Y, float scale, int headsplit) {
  __shared__ float As[64][17];
  __shared__ float Bs[16][65];
  int tid = threadIdx.x;
  int tx = tid & 15, ty = tid >> 4;
  int r0 = blockIdx.y * 64, c0 = blockIdx.x * 64;
  float acc[4][4] = {};
  for (int k0 = 0; k0 < EE; k0 += 16) {
    {
      int i = tid >> 2;
      int kk = (tid & 3) * 4;
      const float4 a = *(const float4*)&X[(size_t)(r0 + i) * EE + k0 + kk];
      As[i][kk] = a.x; As[i][kk+1] = a.y; As[i][kk+2] = a.z; As[i][kk+3] = a.w;
    }
    {
      int kk = tid >> 4;
      int j = (tid & 15) * 4;
      const float4 b = *(const float4*)&W[(size_t)(k0 + kk) * EE + c0 + j];
      Bs[kk][j] = b.x; Bs[kk][j+1] = b.y; Bs[kk][j+2] = b.z; Bs[kk][j+3] = b.w;
    }
    __syncthreads();
    #pragma unroll
    for (int kk = 0; kk < 16; ++kk) {
      float a[4], b[4];
      #pragma unroll
      for (int u = 0; u < 4; ++u) a[u] = As[ty*4+u][kk];
      #pragma unroll
      for (int v = 0; v < 4; ++v) b[v] = Bs[kk][tx*4+v];
      #pragma unroll
      for (int u = 0; u < 4; ++u)
        #pragma unroll
        for (int v = 0; v < 4; ++v) acc[u][v] += a[u]*b[v];
    }
    __syncthreads();
  }
  #pragma unroll
  for (int u = 0; u < 4; ++u) {
    int r = r0 + ty*4 + u;
    #pragma unroll
    for (int v = 0; v < 4; ++v) {
      int c = c0 + tx*4 + v;
      float val = (acc[u][v] + bias[c]) * scale;
      if (headsplit) {
        int b_ = r >> 10, t_ = r & 1023, h_ = c >> 6, d_ = c & 63;
        Y[(((size_t)(b_*HH + h_) * TT) + t_) * DD + d_] = val;
      } else {
        Y[(size_t)r * EE + c] = val;
      }
    }
  }
}

// ---------------- batched QK^T
__global__ __launch_bounds__(256) void k_qk(const float* __restrict__ q,
    const float* __restrict__ k, float* __restrict__ aw) {
  int bh = blockIdx.z;
  int t0 = blockIdx.y * 64, s0 = blockIdx.x * 64;
  if (s0 > t0 + 63) return;
  __shared__ float Qs[64][65];
  __shared__ float Ks[64][65];
  int tid = threadIdx.x;
  const float* qb = q + (size_t)bh * TT * DD;
  const float* kb = k + (size_t)bh * TT * DD;
  #pragma unroll
  for (int u = 0; u < 4; ++u) {
    int fi = tid + u * 256;
    int row = fi >> 4, c4 = (fi & 15) * 4;
    float4 a = *(const float4*)&qb[(size_t)(t0 + row) * DD + c4];
    Qs[row][c4] = a.x; Qs[row][c4+1] = a.y; Qs[row][c4+2] = a.z; Qs[row][c4+3] = a.w;
    float4 b = *(const float4*)&kb[(size_t)(s0 + row) * DD + c4];
    Ks[row][c4] = b.x; Ks[row][c4+1] = b.y; Ks[row][c4+2] = b.z; Ks[row][c4+3] = b.w;
  }
  __syncthreads();
  int tx = tid & 15, ty = tid >> 4;
  float acc[4][4] = {};
  #pragma unroll 8
  for (int kk = 0; kk < 64; ++kk) {
    float a[4], b[4];
    #pragma unroll
    for (int u = 0; u < 4; ++u) a[u] = Qs[ty*4+u][kk];
    #pragma unroll
    for (int v = 0; v < 4; ++v) b[v] = Ks[tx*4+v][kk];
    #pragma unroll
    for (int u = 0; u < 4; ++u)
      #pragma unroll
      for (int v = 0; v < 4; ++v) acc[u][v] += a[u]*b[v];
  }
  float* awb = aw + (size_t)bh * TT * TT;
  #pragma unroll
  for (int u = 0; u < 4; ++u) {
    int t_ = t0 + ty*4 + u;
    #pragma unroll
    for (int v = 0; v < 4; ++v)
      awb[(size_t)t_ * TT + s0 + tx*4 + v] = acc[u][v];
  }
}

// ---------------- per-row softmax stats over causal prefix
__global__ __launch_bounds__(256) void k_rowstats(const float* __restrict__ aw,
    float* __restrict__ Mv, float* __restrict__ Sv) {
  int bh = blockIdx.y;
  int wid = threadIdx.x >> 6, lane = threadIdx.x & 63;
  int t = blockIdx.x * 4 + wid;
  const float* row = aw + ((size_t)bh * TT + t) * TT;
  float vals[16];
  float m = NEGF;
  #pragma unroll
  for (int i = 0; i < 16; ++i) {
    int j = lane + 64*i;
    vals[i] = (j <= t) ? row[j] : NEGF;
    m = fmaxf(m, vals[i]);
  }
  for (int o = 32; o; o >>= 1) m = fmaxf(m, __shfl_xor(m, o));
  float s = 0.f;
  #pragma unroll
  for (int i = 0; i < 16; ++i) {
    int j = lane + 64*i;
    if (j <= t) s += expf(vals[i] - m);
  }
  for (int o = 32; o; o >>= 1) s += __shfl_xor(s, o);
  if (lane == 0) { Mv[(size_t)bh*TT + t] = m; Sv[(size_t)bh*TT + t] = s; }
}

// ---------------- parallel init of heavy-hitter scores
__global__ __launch_bounds__(256) void k_init_acc(const float* __restrict__ aw,
    const float* __restrict__ Mv, const float* __restrict__ Sv,
    float* __restrict__ initacc) {
  int bh = blockIdx.x;
  int c = threadIdx.x;
  float val = 0.f;
  if (c < HB) {
    const float* awb = aw + (size_t)bh * TT * TT;
    const float* Mb = Mv + (size_t)bh * TT;
    const float* Sb = Sv + (size_t)bh * TT;
    for (int i = c; i < HB; ++i)
      val += expf(awb[(size_t)i * TT + c] - Mb[i]) / Sb[i];
  }
  initacc[(size_t)bh * 256 + c] = val;
}

// ---------------- wave-wide min over u32 via DPP (VALU path, no LDS)
// rocPRIM pattern: row_shr 1/2/4/8 then row_bcast15/31; result in lane 63.
#define DPP_HOP(ctrl)                                                        \
  {                                                                          \
    unsigned tt = (unsigned)__builtin_amdgcn_update_dpp(                     \
        (int)0xFFFFFFFFu, (int)x, (ctrl), 0xF, 0xF, false);                  \
    x = x < tt ? x : tt;                                                     \
  }
__device__ __forceinline__ unsigned wave_min_u32(unsigned x) {
  DPP_HOP(0x111)  // row_shr:1
  DPP_HOP(0x112)  // row_shr:2
  DPP_HOP(0x114)  // row_shr:4
  DPP_HOP(0x118)  // row_shr:8
  DPP_HOP(0x142)  // row_bcast:15
  DPP_HOP(0x143)  // row_bcast:31
  return (unsigned)__builtin_amdgcn_readlane((int)x, 63);
}

// ---------------- serial heavy-hitter scan: one wave per bh, no barriers in loop
__device__ __forceinline__ void scan_step(int t, float4 (&P)[4],
    float (&sc)[3], int (&col)[3], bool act2,
    float* __restrict__ rowbuf, const float* __restrict__ Ml,
    const float* __restrict__ SIl, int* __restrict__ ev,
    const float* __restrict__ awb, int lane) {
  float* rb  = rowbuf + (t & 1) * TT;
  float* rbn = rowbuf + ((t + 1) & 1) * TT;
  // early LDS reads (addresses known from previous step; overlap the reduce)
  float r0 = rb[col[0]];
  float r1 = rb[col[1]];
  float r2 = rb[act2 ? col[2] : 0];
  float rd = rb[t];                     // diagonal aw[t][t] (broadcast)
  float Mt = Ml[t], Sit = SIl[t];
  // stage row t+1 into the other LDS buffer; refill the register pipe (row t+3)
  if (t + 1 < TT) {
    float4* w = (float4*)rbn;
    #pragma unroll
    for (int i = 0; i < 4; ++i) w[lane + 64 * i] = P[i];
  }
  if (t + 3 < TT) {
    const float4* src = (const float4*)(awb + (size_t)(t + 3) * TT);
    #pragma unroll
    for (int i = 0; i < 4; ++i) P[i] = src[lane + 64 * i];
  }
  // updates (used only AFTER the reduce — keys use pre-update scores)
  float u0 = expf(r0 - Mt) * Sit;
  float u1 = expf(r1 - Mt) * Sit;
  float u2 = expf(r2 - Mt) * Sit;
  float ud = expf(rd - Mt) * Sit;       // new token's score
  // phase 1: min score (non-negative fp32 -> u32-monotone)
  unsigned b0 = __float_as_uint(sc[0]);
  unsigned b1 = __float_as_uint(sc[1]);
  unsigned b2 = act2 ? __float_as_uint(sc[2]) : 0xFFFFFFFFu;
  unsigned mn = b0 < b1 ? b0 : b1; mn = mn < b2 ? mn : b2;
  unsigned mstar = wave_min_u32(mn);
  // phase 2: among score==mstar, evict the LARGEST col (ref top_k keeps lower idx)
  unsigned c0k = (b0 == mstar) ? (unsigned)(1023 - col[0]) : 0xFFFFFFFFu;
  unsigned c1k = (b1 == mstar) ? (unsigned)(1023 - col[1]) : 0xFFFFFFFFu;
  unsigned c2k = (act2 && b2 == mstar) ? (unsigned)(1023 - col[2]) : 0xFFFFFFFFu;
  unsigned cm = c0k < c1k ? c0k : c1k; cm = cm < c2k ? cm : c2k;
  int cstar = 1023 - (int)wave_min_u32(cm);
  // select
  if (b0 == mstar && col[0] == cstar) { ev[col[0]] = t; col[0] = t; sc[0] = ud; }
  else sc[0] += u0;
  if (b1 == mstar && col[1] == cstar) { ev[col[1]] = t; col[1] = t; sc[1] = ud; }
  else sc[1] += u1;
  if (act2) {
    if (b2 == mstar && col[2] == cstar) { ev[col[2]] = t; col[2] = t; sc[2] = ud; }
    else sc[2] += u2;
  }
}

__global__ __launch_bounds__(64) void k_scan(const float* __restrict__ aw,
    const float* __restrict__ Mv, const float* __restrict__ Sv,
    const float* __restrict__ initacc, int* __restrict__ evict_g) {
  int bh = blockIdx.x;
  int lane = threadIdx.x;
  const float* awb = aw + (size_t)bh * TT * TT;
  __shared__ float rowbuf[2 * TT];
  __shared__ float Ml[TT];
  __shared__ float SIl[TT];
  __shared__ int ev[TT];
  for (int i = lane; i < TT; i += 64) {
    Ml[i] = Mv[(size_t)bh * TT + i];
    SIl[i] = 1.0f / Sv[(size_t)bh * TT + i];
    ev[i] = 0x7fffffff;
  }
  bool act2 = (lane < HB - 128);  // lane < 25
  int col[3]; float sc[3];
  col[0] = lane;        sc[0] = initacc[(size_t)bh * 256 + lane];
  col[1] = 64 + lane;   sc[1] = initacc[(size_t)bh * 256 + 64 + lane];
  col[2] = act2 ? (128 + lane) : -1;
  sc[2] = act2 ? initacc[(size_t)bh * 256 + 128 + lane] : 0.f;
  // row HB into rowbuf[HB&1]; pipeline regs: PA=row HB+1, PB=row HB+2
  {
    float4* w = (float4*)(rowbuf + (HB & 1) * TT);
    const float4* src = (const float4*)(awb + (size_t)HB * TT);
    #pragma unroll
    for (int i = 0; i < 4; ++i) w[lane + 64 * i] = src[lane + 64 * i];
  }
  float4 PA[4], PB[4];
  {
    const float4* sa = (const float4*)(awb + (size_t)(HB + 1) * TT);
    const float4* sb = (const float4*)(awb + (size_t)(HB + 2) * TT);
    #pragma unroll
    for (int i = 0; i < 4; ++i) { PA[i] = sa[lane + 64 * i]; PB[i] = sb[lane + 64 * i]; }
  }
  __syncthreads();

  scan_step(HB, PA, sc, col, act2, rowbuf, Ml, SIl, ev, awb, lane);      // t=153
  #pragma unroll 1
  for (int t = HB + 1; t < TT - 2; t += 2) {
    scan_step(t,     PB, sc, col, act2, rowbuf, Ml, SIl, ev, awb, lane);
    scan_step(t + 1, PA, sc, col, act2, rowbuf, Ml, SIl, ev, awb, lane);
  }
  scan_step(TT - 2, PB, sc, col, act2, rowbuf, Ml, SIl, ev, awb, lane);  // t=1022
  scan_step(TT - 1, PA, sc, col, act2, rowbuf, Ml, SIl, ev, awb, lane);  // t=1023

  __syncthreads();
  int4* dst = (int4*)(evict_g + (size_t)bh * TT);
  const int4* srcv = (const int4*)ev;
  #pragma unroll
  for (int i = 0; i < 4; ++i) dst[lane + 64 * i] = srcv[lane + 64 * i];
}

// ---------------- masked softmax + PV using evict_time
__global__ __launch_bounds__(256) void k_attn(const float* __restrict__ aw,
    const int* __restrict__ evict_g,
    const float* __restrict__ v, float* __restrict__ ao) {
  int bh = blockIdx.y, t = blockIdx.x;
  int tid = threadIdx.x;
  const float* row = aw + ((size_t)bh * TT + t) * TT;
  __shared__ float p[TT];
  __shared__ float red[8];
  __shared__ float pv[4][64];
  __shared__ int et[TT];
  ((int4*)et)[tid] = ((const int4*)(evict_g + (size_t)bh * TT))[tid];
  __syncthreads();

  float vals[4]; bool ok[4];
  float m = NEGF;
  #pragma unroll
  for (int i = 0; i < 4; ++i) {
    int j = tid + 256*i;
    bool allow = (j <= t) && ((et[j] > t) || (j + RECW >= t));
    ok[i] = allow;
    vals[i] = allow ? row[j] : NEGF;
    m = fmaxf(m, vals[i]);
  }
  for (int o = 32; o; o >>= 1) m = fmaxf(m, __shfl_xor(m, o));
  int wid = tid >> 6;
  if ((tid & 63) == 0) red[wid] = m;
  __syncthreads();
  m = fmaxf(fmaxf(red[0], red[1]), fmaxf(red[2], red[3]));

  float s = 0.f;
  float e[4];
  #pragma unroll
  for (int i = 0; i < 4; ++i) { e[i] = ok[i] ? expf(vals[i] - m) : 0.f; s += e[i]; }
  for (int o = 32; o; o >>= 1) s += __shfl_xor(s, o);
  if ((tid & 63) == 0) red[4 + wid] = s;
  __syncthreads();
  s = red[4] + red[5] + red[6] + red[7];
  float inv = 1.f / s;
  #pragma unroll
  for (int i = 0; i < 4; ++i) p[tid + 256*i] = e[i] * inv;
  __syncthreads();

  int g = tid >> 6, d = tid & 63;
  const float* vb = v + (size_t)bh * TT * DD;
  float acc = 0.f;
  int lim = t + 1 - g*256; if (lim > 256) lim = 256;
  for (int i = 0; i < lim; ++i) {
    int j = g * 256 + i;
    acc += p[j] * vb[(size_t)j * DD + d];
  }
  pv[g][d] = acc;
  __syncthreads();
  if (tid < 64) {
    float r = pv[0][tid] + pv[1][tid] + pv[2][tid] + pv[3][tid];
    int b_ = bh >> 4, h_ = bh & 15;
    ao[((size_t)b_ * TT + t) * EE + h_ * DD + tid] = r;
  }
}

extern "C" void kernel_launch(void* const* d_in, const int* in_sizes, int n_in,
                              void* d_out, int out_size, void* d_ws, size_t ws_size,
                              hipStream_t stream) {
  const float* hs = (const float*)d_in[0];
  const float* Wq = (const float*)d_in[2];
  const float* bq = (const float*)d_in[3];
  const float* Wk = (const float*)d_in[4];
  const float* bk = (const float*)d_in[5];
  const float* Wv = (const float*)d_in[6];
  const float* bv = (const float*)d_in[7];
  const float* Wo = (const float*)d_in[8];
  const float* bo = (const float*)d_in[9];
  float* out = (float*)d_out;

  float* ws = (float*)d_ws;
  float* q  = ws + OFF_Q;
  float* k  = ws + OFF_K;
  float* v  = ws + OFF_V;
  float* aw = ws + OFF_AW;
  float* Mv = ws + OFF_M;
  float* Sv = ws + OFF_S;
  float* ao = ws + OFF_AO;
  float* initacc = ws + OFF_END;
  int* evict = (int*)(ws + OFF_END + (size_t)BHN * 256);

  dim3 gproj(16, 32);
  k_proj<<<gproj, 256, 0, stream>>>(hs, Wq, bq, q, 0.125f, 1);
  k_proj<<<gproj, 256, 0, stream>>>(hs, Wk, bk, k, 1.0f, 1);
  k_proj<<<gproj, 256, 0, stream>>>(hs, Wv, bv, v, 1.0f, 1);

  dim3 gqk(16, 16, BHN);
  k_qk<<<gqk, 256, 0, stream>>>(q, k, aw);

  dim3 grs(TT/4, BHN);
  k_rowstats<<<grs, 256, 0, stream>>>(aw, Mv, Sv);

  k_init_acc<<<BHN, 256, 0, stream>>>(aw, Mv, Sv, initacc);

  k_scan<<<BHN, 64, 0, stream>>>(aw, Mv, Sv, initacc, evict);

  dim3 gat(TT, BHN);
  k_attn<<<gat, 256, 0, stream>>>(aw, evict, v, ao);

  k_proj<<<gproj, 256, 0, stream>>>(ao, Wo, bo, out, 1.0f, 0);
}